// Round 1
// baseline (9703.864 us; speedup 1.0000x reference)
//
#include <hip/hip_runtime.h>
#include <hip/hip_bf16.h>

// SAGEClassifier: h[50000,256] --conv1(LSTM-agg)--> h1[50000,128] --conv2--> h2[50000,128]
//   --segment_max(256 graphs)--> hg[256,128] --linear--> out[256,10]
//
// Strategy (baseline round):
//  - Hin = h @ W_ih.T + (b_ih+b_hh) precomputed ONCE per layer (16x less work than
//    per-(node,step) input transform), stored bf16 in ws, gathered per step.
//  - LSTM recurrent GEMM: fused kernel, 32 nodes/block, h-state in LDS, c+gate accs
//    in registers, W_hh pre-transposed to k-major (coalesced L2-resident reads).
//  - everything else fp32.

#define NNODES  50000
#define DEG     16
#define INDIM   256
#define HIDDIM  128
#define NCLS    10
#define NGRAPH  256

typedef __hip_bfloat16 bf16;

__device__ __forceinline__ float sigf(float x) {
    x = fminf(fmaxf(x, -30.f), 30.f);
    return 1.0f / (1.0f + __expf(-x));
}
__device__ __forceinline__ float tanhfast(float x) {
    x = fminf(fmaxf(x, -15.f), 15.f);
    float e = __expf(2.0f * x);
    return (e - 1.0f) / (e + 1.0f);
}

// Wt[k*rows + r] = W[r*cols + k]
__global__ void transpose_k(const float* __restrict__ W, float* __restrict__ Wt,
                            int rows, int cols) {
    int idx = blockIdx.x * 256 + threadIdx.x;
    if (idx >= rows * cols) return;
    int r = idx % rows;
    int k = idx / rows;
    Wt[idx] = W[r * cols + k];
}

// C[m,j] = sum_k A[m,k]*B[j,k] (+ A2.B2 if DUAL) + bias0[j] (+bias1[j]); opt relu; opt bf16 store
template<bool RELU, bool DUAL, bool BF16OUT>
__global__ __launch_bounds__(256) void gemm_nt(
    const float* __restrict__ A, const float* __restrict__ B,
    const float* __restrict__ A2, const float* __restrict__ B2,
    const float* __restrict__ bias0, const float* __restrict__ bias1,
    void* __restrict__ Cout, int M, int Ncol, int K, int K2)
{
    __shared__ float As[16][68];   // [k][m], pad 4 keeps float4 align + banks spread
    __shared__ float Bs[16][68];
    const int tid = threadIdx.x;
    const int m0 = blockIdx.y * 64;
    const int j0 = blockIdx.x * 64;
    const int tx = tid & 15;        // col group
    const int ty = tid >> 4;        // row group
    const int am = tid >> 2;        // staging row 0..63
    const int ak = (tid & 3) * 4;   // staging k 0,4,8,12
    float c[4][4] = {};

    const int npass = DUAL ? 2 : 1;
    for (int pass = 0; pass < npass; ++pass) {
        const float* Ap = (DUAL && pass) ? A2 : A;
        const float* Bp = (DUAL && pass) ? B2 : B;
        const int Kp = (DUAL && pass) ? K2 : K;
        for (int kk = 0; kk < Kp; kk += 16) {
            float4 av = make_float4(0.f, 0.f, 0.f, 0.f);
            float4 bv = make_float4(0.f, 0.f, 0.f, 0.f);
            if (m0 + am < M)    av = *(const float4*)&Ap[(size_t)(m0 + am) * Kp + kk + ak];
            if (j0 + am < Ncol) bv = *(const float4*)&Bp[(size_t)(j0 + am) * Kp + kk + ak];
            __syncthreads();   // previous tile fully consumed
            As[ak + 0][am] = av.x; As[ak + 1][am] = av.y;
            As[ak + 2][am] = av.z; As[ak + 3][am] = av.w;
            Bs[ak + 0][am] = bv.x; Bs[ak + 1][am] = bv.y;
            Bs[ak + 2][am] = bv.z; Bs[ak + 3][am] = bv.w;
            __syncthreads();
            #pragma unroll
            for (int k = 0; k < 16; ++k) {
                float4 a = *(const float4*)&As[k][ty * 4];
                float4 b = *(const float4*)&Bs[k][tx * 4];
                c[0][0] = fmaf(a.x, b.x, c[0][0]); c[0][1] = fmaf(a.x, b.y, c[0][1]);
                c[0][2] = fmaf(a.x, b.z, c[0][2]); c[0][3] = fmaf(a.x, b.w, c[0][3]);
                c[1][0] = fmaf(a.y, b.x, c[1][0]); c[1][1] = fmaf(a.y, b.y, c[1][1]);
                c[1][2] = fmaf(a.y, b.z, c[1][2]); c[1][3] = fmaf(a.y, b.w, c[1][3]);
                c[2][0] = fmaf(a.z, b.x, c[2][0]); c[2][1] = fmaf(a.z, b.y, c[2][1]);
                c[2][2] = fmaf(a.z, b.z, c[2][2]); c[2][3] = fmaf(a.z, b.w, c[2][3]);
                c[3][0] = fmaf(a.w, b.x, c[3][0]); c[3][1] = fmaf(a.w, b.y, c[3][1]);
                c[3][2] = fmaf(a.w, b.z, c[3][2]); c[3][3] = fmaf(a.w, b.w, c[3][3]);
            }
        }
    }
    #pragma unroll
    for (int i = 0; i < 4; ++i) {
        int m = m0 + ty * 4 + i;
        if (m >= M) continue;
        #pragma unroll
        for (int jj = 0; jj < 4; ++jj) {
            int j = j0 + tx * 4 + jj;
            if (j >= Ncol) continue;
            float v = c[i][jj];
            if (bias0) v += bias0[j];
            if (bias1) v += bias1[j];
            if (RELU) v = fmaxf(v, 0.f);
            if (BF16OUT) ((bf16*)Cout)[(size_t)m * Ncol + j] = __float2bfloat16(v);
            else         ((float*)Cout)[(size_t)m * Ncol + j] = v;
        }
    }
}

// Fused LSTM over DEG steps. D=hidden dim, TNODE nodes/block, 256 threads.
// Thread owns gate-dim j = tid%D for NPT = TNODE/(256/D) nodes.
// gates[node][j+g*D] = Hin[nbr(node,t)][j+g*D] + sum_k h[node][k]*Wt[k][j+g*D]
template<int D, int TNODE>
__global__ __launch_bounds__(256, 2) void lstm_k(
    const bf16* __restrict__ Hin,    // [Nn, 4D], bias folded in
    const float* __restrict__ Wt,    // [D, 4D] = W_hh transposed (k-major)
    const int* __restrict__ nidx,    // [Nn, DEG]
    float* __restrict__ hout,        // [Nn, D]
    int Nn)
{
    constexpr int FD = 4 * D;
    constexpr int REP = 256 / D;        // 1 (D=256) or 2 (D=128)
    constexpr int NPT = TNODE / REP;    // 32 both configs
    const int tid = threadIdx.x;
    const int j = tid % D;
    const int rep = tid / D;
    const int nodeBase = blockIdx.x * TNODE;
    const int lbase = rep * NPT;

    __shared__ float h_lds[TNODE][D];       // 32 KB
    __shared__ int   nid_lds[TNODE * DEG];

    for (int i = tid; i < TNODE * DEG; i += 256) {
        int gidx = nodeBase * DEG + i;
        nid_lds[i] = (gidx < Nn * DEG) ? nidx[gidx] : 0;
    }
    float creg[NPT];
    #pragma unroll
    for (int n = 0; n < NPT; ++n) creg[n] = 0.f;
    __syncthreads();

    for (int t = 0; t < DEG; ++t) {
        float a0[NPT], a1[NPT], a2[NPT], a3[NPT];
        // gather input-transform rows (bias already folded)
        #pragma unroll
        for (int n = 0; n < NPT; ++n) {
            int nbr = nid_lds[(lbase + n) * DEG + t];
            const bf16* hp = Hin + (size_t)nbr * FD;
            a0[n] = __bfloat162float(hp[j]);
            a1[n] = __bfloat162float(hp[j + D]);
            a2[n] = __bfloat162float(hp[j + 2 * D]);
            a3[n] = __bfloat162float(hp[j + 3 * D]);
        }
        if (t > 0) {
            // recurrent GEMM: acc += h_state @ W_hh.T  (Wt k-major: coalesced, L2-resident)
            #pragma unroll 2
            for (int k = 0; k < D; ++k) {
                float w0 = Wt[k * FD + j];
                float w1 = Wt[k * FD + D + j];
                float w2 = Wt[k * FD + 2 * D + j];
                float w3 = Wt[k * FD + 3 * D + j];
                #pragma unroll
                for (int n = 0; n < NPT; ++n) {
                    float hv = h_lds[lbase + n][k];   // wave-uniform broadcast read
                    a0[n] = fmaf(w0, hv, a0[n]);
                    a1[n] = fmaf(w1, hv, a1[n]);
                    a2[n] = fmaf(w2, hv, a2[n]);
                    a3[n] = fmaf(w3, hv, a3[n]);
                }
            }
            __syncthreads();   // all h_lds reads done before overwrite
        }
        #pragma unroll
        for (int n = 0; n < NPT; ++n) {
            float ig = sigf(a0[n]);
            float fg = sigf(a1[n]);
            float gg = tanhfast(a2[n]);
            float og = sigf(a3[n]);
            float cv = fg * creg[n] + ig * gg;
            creg[n] = cv;
            h_lds[lbase + n][j] = og * tanhfast(cv);
        }
        __syncthreads();
    }
    #pragma unroll
    for (int n = 0; n < NPT; ++n) {
        int node = nodeBase + lbase + n;
        if (node < Nn) hout[(size_t)node * D + j] = h_lds[lbase + n][j];
    }
}

// per-graph max over sorted graph_ids (binary-search bounds)
__global__ void segmax_k(const float* __restrict__ h2, const int* __restrict__ gid,
                         float* __restrict__ hg, int Nn) {
    int g = blockIdx.x;
    int d = threadIdx.x;   // 128
    __shared__ int sb[2];
    if (d < 2) {
        int target = g + d;
        int lo = 0, hi = Nn;
        while (lo < hi) { int mid = (lo + hi) >> 1; if (gid[mid] < target) lo = mid + 1; else hi = mid; }
        sb[d] = lo;
    }
    __syncthreads();
    int lo = sb[0], hi = sb[1];
    float m = -INFINITY;   // jax segment_max identity
    for (int r = lo; r < hi; ++r) m = fmaxf(m, h2[(size_t)r * HIDDIM + d]);
    hg[g * HIDDIM + d] = m;
}

__global__ void cls_k(const float* __restrict__ hg, const float* __restrict__ W,
                      const float* __restrict__ b, float* __restrict__ out) {
    int idx = blockIdx.x * 256 + threadIdx.x;
    if (idx >= NGRAPH * NCLS) return;
    int g = idx / NCLS, cc = idx % NCLS;
    float s = b[cc];
    const float* hp = hg + g * HIDDIM;
    const float* wp = W + cc * HIDDIM;
    #pragma unroll 8
    for (int k = 0; k < HIDDIM; ++k) s = fmaf(hp[k], wp[k], s);
    out[idx] = s;
}

extern "C" void kernel_launch(void* const* d_in, const int* in_sizes, int n_in,
                              void* d_out, int out_size, void* d_ws, size_t ws_size,
                              hipStream_t stream)
{
    const float* h       = (const float*)d_in[0];
    const int*   nidx    = (const int*)d_in[1];
    const int*   gids    = (const int*)d_in[2];
    const float* W_ih1   = (const float*)d_in[3];
    const float* W_hh1   = (const float*)d_in[4];
    const float* b_ih1   = (const float*)d_in[5];
    const float* b_hh1   = (const float*)d_in[6];
    const float* W_self1 = (const float*)d_in[7];
    const float* W_neigh1= (const float*)d_in[8];
    const float* b1      = (const float*)d_in[9];
    const float* W_ih2   = (const float*)d_in[10];
    const float* W_hh2   = (const float*)d_in[11];
    const float* b_ih2   = (const float*)d_in[12];
    const float* b_hh2   = (const float*)d_in[13];
    const float* W_self2 = (const float*)d_in[14];
    const float* W_neigh2= (const float*)d_in[15];
    const float* b2      = (const float*)d_in[16];
    const float* W_cls   = (const float*)d_in[17];
    const float* b_cls   = (const float*)d_in[18];
    float* out = (float*)d_out;

    // ws layout (total 206,241,792 bytes)
    char* ws = (char*)d_ws;
    bf16*  Hin    = (bf16*)(ws);                  // 50000*1024*2 = 102,400,000 (conv1; conv2 reuses)
    float* hneigh = (float*)(ws + 102400000);     // 50000*256*4  =  51,200,000 (conv1; conv2 reuses)
    float* h1     = (float*)(ws + 153600000);     // 50000*128*4  =  25,600,000
    float* h2     = (float*)(ws + 179200000);     // 25,600,000
    float* hg     = (float*)(ws + 204800000);     // 131,072
    float* Wt1    = (float*)(ws + 204931072);     // 1,048,576
    float* Wt2    = (float*)(ws + 205979648);     // 262,144

    // W_hh transposes to k-major (tiny)
    transpose_k<<<dim3((1024 * 256 + 255) / 256), 256, 0, stream>>>(W_hh1, Wt1, 1024, 256);
    transpose_k<<<dim3((512 * 128 + 255) / 256), 256, 0, stream>>>(W_hh2, Wt2, 512, 128);

    const int MB = (NNODES + 63) / 64;

    // ---- conv1 ----
    gemm_nt<false, false, true><<<dim3(1024 / 64, MB), 256, 0, stream>>>(
        h, W_ih1, nullptr, nullptr, b_ih1, b_hh1, Hin, NNODES, 1024, 256, 0);
    lstm_k<256, 32><<<dim3((NNODES + 31) / 32), 256, 0, stream>>>(Hin, Wt1, nidx, hneigh, NNODES);
    gemm_nt<true, true, false><<<dim3(HIDDIM / 64, MB), 256, 0, stream>>>(
        h, W_self1, hneigh, W_neigh1, b1, nullptr, h1, NNODES, HIDDIM, 256, 256);

    // ---- conv2 ----
    gemm_nt<false, false, true><<<dim3(512 / 64, MB), 256, 0, stream>>>(
        h1, W_ih2, nullptr, nullptr, b_ih2, b_hh2, Hin, NNODES, 512, 128, 0);
    lstm_k<128, 64><<<dim3((NNODES + 63) / 64), 256, 0, stream>>>(Hin, Wt2, nidx, hneigh, NNODES);
    gemm_nt<true, true, false><<<dim3(HIDDIM / 64, MB), 256, 0, stream>>>(
        h1, W_self2, hneigh, W_neigh2, b2, nullptr, h2, NNODES, HIDDIM, 128, 128);

    // ---- readout ----
    segmax_k<<<dim3(NGRAPH), 128, 0, stream>>>(h2, gids, hg, NNODES);
    cls_k<<<dim3((NGRAPH * NCLS + 255) / 256), 256, 0, stream>>>(hg, W_cls, b_cls, out);
}

// Round 2
// 6537.078 us; speedup vs baseline: 1.4844x; 1.4844x over previous
//
#include <hip/hip_runtime.h>
#include <hip/hip_bf16.h>

// SAGEClassifier: h[50000,256] --conv1(LSTM-agg)--> h1[50000,128] --conv2--> h2[50000,128]
//   --segment_max(256 graphs)--> hg[256,128] --linear--> out[256,10]
//
// Round 1: LSTM recurrent GEMM -> MFMA (v_mfma_f32_16x16x32_bf16).
//  - per block: 64 nodes, 4 waves, N-split by wave so i/f/g/o of a (node,d) share a lane.
//  - h_state bf16 in LDS (stride D+8: 16B-aligned rows, conflict-free ds_read_b128).
//  - W_hh bf16 row-major [4D][D], streamed from L2 as B-fragments (m97 pattern).
//  - Hin slice staged to LDS per 64-d chunk (reg-staged vec loads); acc init from it.
//  - h_new deferred in regs to end of step (no LDS double buffer; 2 blocks/CU).
//  - gemm_nt (xform/fc) still fp32 this round -- isolate the MFMA change.

#define NNODES  50000
#define DEG     16
#define INDIM   256
#define HIDDIM  128
#define NCLS    10
#define NGRAPH  256

typedef __hip_bfloat16 bf16;
typedef short bf16x8 __attribute__((ext_vector_type(8)));
typedef float f32x4  __attribute__((ext_vector_type(4)));

__device__ __forceinline__ float sigf(float x) {
    x = fminf(fmaxf(x, -30.f), 30.f);
    return 1.0f / (1.0f + __expf(-x));
}
__device__ __forceinline__ float tanhfast(float x) {
    x = fminf(fmaxf(x, -15.f), 15.f);
    float e = __expf(2.0f * x);
    return (e - 1.0f) / (e + 1.0f);
}
__device__ __forceinline__ float b2f(unsigned short u) {
    return __uint_as_float(((unsigned)u) << 16);
}
__device__ __forceinline__ unsigned short f2b(float f) {  // RNE bf16
    unsigned u = __float_as_uint(f);
    return (unsigned short)((u + 0x7FFF + ((u >> 16) & 1)) >> 16);
}

__global__ void f2bf_k(const float* __restrict__ in, unsigned short* __restrict__ out, int n) {
    int i = blockIdx.x * 256 + threadIdx.x;
    if (i < n) out[i] = f2b(in[i]);
}

// ---------------- fp32 tiled GEMM (unchanged from round 0) ----------------
template<bool RELU, bool DUAL, bool BF16OUT>
__global__ __launch_bounds__(256) void gemm_nt(
    const float* __restrict__ A, const float* __restrict__ B,
    const float* __restrict__ A2, const float* __restrict__ B2,
    const float* __restrict__ bias0, const float* __restrict__ bias1,
    void* __restrict__ Cout, int M, int Ncol, int K, int K2)
{
    __shared__ float As[16][68];
    __shared__ float Bs[16][68];
    const int tid = threadIdx.x;
    const int m0 = blockIdx.y * 64;
    const int j0 = blockIdx.x * 64;
    const int tx = tid & 15;
    const int ty = tid >> 4;
    const int am = tid >> 2;
    const int ak = (tid & 3) * 4;
    float c[4][4] = {};

    const int npass = DUAL ? 2 : 1;
    for (int pass = 0; pass < npass; ++pass) {
        const float* Ap = (DUAL && pass) ? A2 : A;
        const float* Bp = (DUAL && pass) ? B2 : B;
        const int Kp = (DUAL && pass) ? K2 : K;
        for (int kk = 0; kk < Kp; kk += 16) {
            float4 av = make_float4(0.f, 0.f, 0.f, 0.f);
            float4 bv = make_float4(0.f, 0.f, 0.f, 0.f);
            if (m0 + am < M)    av = *(const float4*)&Ap[(size_t)(m0 + am) * Kp + kk + ak];
            if (j0 + am < Ncol) bv = *(const float4*)&Bp[(size_t)(j0 + am) * Kp + kk + ak];
            __syncthreads();
            As[ak + 0][am] = av.x; As[ak + 1][am] = av.y;
            As[ak + 2][am] = av.z; As[ak + 3][am] = av.w;
            Bs[ak + 0][am] = bv.x; Bs[ak + 1][am] = bv.y;
            Bs[ak + 2][am] = bv.z; Bs[ak + 3][am] = bv.w;
            __syncthreads();
            #pragma unroll
            for (int k = 0; k < 16; ++k) {
                float4 a = *(const float4*)&As[k][ty * 4];
                float4 b = *(const float4*)&Bs[k][tx * 4];
                c[0][0] = fmaf(a.x, b.x, c[0][0]); c[0][1] = fmaf(a.x, b.y, c[0][1]);
                c[0][2] = fmaf(a.x, b.z, c[0][2]); c[0][3] = fmaf(a.x, b.w, c[0][3]);
                c[1][0] = fmaf(a.y, b.x, c[1][0]); c[1][1] = fmaf(a.y, b.y, c[1][1]);
                c[1][2] = fmaf(a.y, b.z, c[1][2]); c[1][3] = fmaf(a.y, b.w, c[1][3]);
                c[2][0] = fmaf(a.z, b.x, c[2][0]); c[2][1] = fmaf(a.z, b.y, c[2][1]);
                c[2][2] = fmaf(a.z, b.z, c[2][2]); c[2][3] = fmaf(a.z, b.w, c[2][3]);
                c[3][0] = fmaf(a.w, b.x, c[3][0]); c[3][1] = fmaf(a.w, b.y, c[3][1]);
                c[3][2] = fmaf(a.w, b.z, c[3][2]); c[3][3] = fmaf(a.w, b.w, c[3][3]);
            }
        }
    }
    #pragma unroll
    for (int i = 0; i < 4; ++i) {
        int m = m0 + ty * 4 + i;
        if (m >= M) continue;
        #pragma unroll
        for (int jj = 0; jj < 4; ++jj) {
            int j = j0 + tx * 4 + jj;
            if (j >= Ncol) continue;
            float v = c[i][jj];
            if (bias0) v += bias0[j];
            if (bias1) v += bias1[j];
            if (RELU) v = fmaxf(v, 0.f);
            if (BF16OUT) ((bf16*)Cout)[(size_t)m * Ncol + j] = __float2bfloat16(v);
            else         ((float*)Cout)[(size_t)m * Ncol + j] = v;
        }
    }
}

// ---------------- MFMA fused LSTM ----------------
// Block: 64 nodes, 256 threads (4 waves). Wave w owns d-cols [w*16, w*16+16) of each
// 64-d chunk, across all 4 gates. C-fragment: node = m*16 + (lane>>4)*4 + reg,
// d = dc*64 + w*16 + (lane&15)  -> i/f/g/o of one (node,d) in one lane, same reg.
template<int D>
__global__ __launch_bounds__(256, 2) void lstm_mfma(
    const unsigned short* __restrict__ Hin,   // [Nn,4D] bf16 bits (bias folded)
    const unsigned short* __restrict__ Wb,    // [4D,D] bf16 bits (W_hh row-major)
    const int* __restrict__ nidx,             // [Nn,DEG]
    float* __restrict__ hout,                 // [Nn,D]
    int Nn)
{
    constexpr int FD  = 4 * D;
    constexpr int KCH = D / 32;   // K chunks of 32
    constexpr int DCH = D / 64;   // d chunks of 64
    constexpr int LDA = D + 8;    // hS stride: 16B-aligned rows, spread banks
    constexpr int LDH = 264;      // hinS stride (4 gates x 64 cols + 8 pad)

    __shared__ unsigned short hS[64 * LDA];
    __shared__ unsigned short hinS[64 * LDH];
    __shared__ int nidS[64 * DEG];

    const int tid  = threadIdx.x;
    const int wid  = tid >> 6;
    const int lane = tid & 63;
    const int lg   = lane >> 4;
    const int lr   = lane & 15;
    const int nb   = blockIdx.x * 64;

    for (int i = tid; i < 64 * DEG; i += 256) {
        int node = nb + (i >> 4);
        nidS[i] = (node < Nn) ? nidx[node * DEG + (i & 15)] : 0;
    }

    float c[DCH][4][4];
    unsigned short hn[DCH][4][4];
    #pragma unroll
    for (int dc = 0; dc < DCH; ++dc)
        #pragma unroll
        for (int m = 0; m < 4; ++m)
            #pragma unroll
            for (int r = 0; r < 4; ++r) c[dc][m][r] = 0.f;
    __syncthreads();

    for (int t = 0; t < DEG; ++t) {
        #pragma unroll
        for (int dc = 0; dc < DCH; ++dc) {
            // ---- stage Hin slice: 64 rows x (4 gates x 64 cols) bf16 ----
            __syncthreads();   // hinS free (prev readers done)
            uint4 stg[8];
            #pragma unroll
            for (int it = 0; it < 8; ++it) {
                int i = tid + it * 256;
                int r = i >> 5, s = i & 31, g = s >> 3, c8 = s & 7;
                int nbr = nidS[r * DEG + t];
                stg[it] = *(const uint4*)&Hin[(size_t)nbr * FD + g * D + dc * 64 + c8 * 8];
            }
            #pragma unroll
            for (int it = 0; it < 8; ++it) {
                int i = tid + it * 256;
                int r = i >> 5, s = i & 31;
                *(uint4*)&hinS[r * LDH + s * 8] = stg[it];
            }
            __syncthreads();

            // ---- acc init from gathered input transform ----
            f32x4 acc[4][4];   // [gate][mtile]
            #pragma unroll
            for (int g = 0; g < 4; ++g)
                #pragma unroll
                for (int m = 0; m < 4; ++m)
                    #pragma unroll
                    for (int r = 0; r < 4; ++r)
                        acc[g][m][r] = b2f(hinS[(m * 16 + lg * 4 + r) * LDH + g * 64 + wid * 16 + lr]);

            // ---- recurrent GEMM: acc += h_state @ W_hh^T (wave's col slice) ----
            if (t > 0) {
                #pragma unroll
                for (int kk = 0; kk < KCH; ++kk) {
                    bf16x8 b[4];
                    #pragma unroll
                    for (int g = 0; g < 4; ++g)
                        b[g] = *(const bf16x8*)&Wb[(size_t)(g * D + dc * 64 + wid * 16 + lr) * D + kk * 32 + lg * 8];
                    #pragma unroll
                    for (int m = 0; m < 4; ++m) {
                        bf16x8 a = *(const bf16x8*)&hS[(m * 16 + lr) * LDA + kk * 32 + lg * 8];
                        #pragma unroll
                        for (int g = 0; g < 4; ++g)
                            acc[g][m] = __builtin_amdgcn_mfma_f32_16x16x32_bf16(a, b[g], acc[g][m], 0, 0, 0);
                    }
                }
            }

            // ---- LSTM nonlinearity (per-lane; i/f/g/o co-located) ----
            #pragma unroll
            for (int m = 0; m < 4; ++m)
                #pragma unroll
                for (int r = 0; r < 4; ++r) {
                    float ig = sigf(acc[0][m][r]);
                    float fg = sigf(acc[1][m][r]);
                    float gg = tanhfast(acc[2][m][r]);
                    float og = sigf(acc[3][m][r]);
                    float cv = fg * c[dc][m][r] + ig * gg;
                    c[dc][m][r] = cv;
                    hn[dc][m][r] = f2b(og * tanhfast(cv));
                }
        }

        // ---- deferred h_state write (all waves' A-reads of hS are done) ----
        __syncthreads();
        if (t < DEG - 1) {
            #pragma unroll
            for (int dc = 0; dc < DCH; ++dc)
                #pragma unroll
                for (int m = 0; m < 4; ++m)
                    #pragma unroll
                    for (int r = 0; r < 4; ++r)
                        hS[(m * 16 + lg * 4 + r) * LDA + dc * 64 + wid * 16 + lr] = hn[dc][m][r];
        }
        // next iteration's first __syncthreads orders these writes vs reads
    }

    #pragma unroll
    for (int dc = 0; dc < DCH; ++dc)
        #pragma unroll
        for (int m = 0; m < 4; ++m)
            #pragma unroll
            for (int r = 0; r < 4; ++r) {
                int node = nb + m * 16 + lg * 4 + r;
                if (node < Nn)
                    hout[(size_t)node * D + dc * 64 + wid * 16 + lr] = b2f(hn[dc][m][r]);
            }
}

// ---------------- readout ----------------
__global__ void segmax_k(const float* __restrict__ h2, const int* __restrict__ gid,
                         float* __restrict__ hg, int Nn) {
    int g = blockIdx.x;
    int d = threadIdx.x;   // 128
    __shared__ int sb[2];
    if (d < 2) {
        int target = g + d;
        int lo = 0, hi = Nn;
        while (lo < hi) { int mid = (lo + hi) >> 1; if (gid[mid] < target) lo = mid + 1; else hi = mid; }
        sb[d] = lo;
    }
    __syncthreads();
    int lo = sb[0], hi = sb[1];
    float m = -INFINITY;
    for (int r = lo; r < hi; ++r) m = fmaxf(m, h2[(size_t)r * HIDDIM + d]);
    hg[g * HIDDIM + d] = m;
}

__global__ void cls_k(const float* __restrict__ hg, const float* __restrict__ W,
                      const float* __restrict__ b, float* __restrict__ out) {
    int idx = blockIdx.x * 256 + threadIdx.x;
    if (idx >= NGRAPH * NCLS) return;
    int g = idx / NCLS, cc = idx % NCLS;
    float s = b[cc];
    const float* hp = hg + g * HIDDIM;
    const float* wp = W + cc * HIDDIM;
    #pragma unroll 8
    for (int k = 0; k < HIDDIM; ++k) s = fmaf(hp[k], wp[k], s);
    out[idx] = s;
}

extern "C" void kernel_launch(void* const* d_in, const int* in_sizes, int n_in,
                              void* d_out, int out_size, void* d_ws, size_t ws_size,
                              hipStream_t stream)
{
    const float* h       = (const float*)d_in[0];
    const int*   nidx    = (const int*)d_in[1];
    const int*   gids    = (const int*)d_in[2];
    const float* W_ih1   = (const float*)d_in[3];
    const float* W_hh1   = (const float*)d_in[4];
    const float* b_ih1   = (const float*)d_in[5];
    const float* b_hh1   = (const float*)d_in[6];
    const float* W_self1 = (const float*)d_in[7];
    const float* W_neigh1= (const float*)d_in[8];
    const float* b1      = (const float*)d_in[9];
    const float* W_ih2   = (const float*)d_in[10];
    const float* W_hh2   = (const float*)d_in[11];
    const float* b_ih2   = (const float*)d_in[12];
    const float* b_hh2   = (const float*)d_in[13];
    const float* W_self2 = (const float*)d_in[14];
    const float* W_neigh2= (const float*)d_in[15];
    const float* b2      = (const float*)d_in[16];
    const float* W_cls   = (const float*)d_in[17];
    const float* b_cls   = (const float*)d_in[18];
    float* out = (float*)d_out;

    // ws layout (16B-aligned chunks)
    char* ws = (char*)d_ws;
    unsigned short* Hin    = (unsigned short*)(ws);            // 102,400,000
    float*          hneigh = (float*)(ws + 102400000);         //  51,200,000
    float*          h1     = (float*)(ws + 153600000);         //  25,600,000
    float*          h2     = (float*)(ws + 179200000);         //  25,600,000
    float*          hg     = (float*)(ws + 204800000);         //     131,072
    unsigned short* Wb1    = (unsigned short*)(ws + 204931072);//     524,288
    unsigned short* Wb2    = (unsigned short*)(ws + 205455360);//     131,072

    // W_hh -> bf16 (row-major kept: B-fragment source)
    f2bf_k<<<dim3((262144 + 255) / 256), 256, 0, stream>>>(W_hh1, Wb1, 262144);
    f2bf_k<<<dim3((65536 + 255) / 256), 256, 0, stream>>>(W_hh2, Wb2, 65536);

    const int MB = (NNODES + 63) / 64;
    const int NB = (NNODES + 63) / 64;   // 782 LSTM blocks

    // ---- conv1 ----
    gemm_nt<false, false, true><<<dim3(1024 / 64, MB), 256, 0, stream>>>(
        h, W_ih1, nullptr, nullptr, b_ih1, b_hh1, Hin, NNODES, 1024, 256, 0);
    lstm_mfma<256><<<dim3(NB), 256, 0, stream>>>(Hin, Wb1, nidx, hneigh, NNODES);
    gemm_nt<true, true, false><<<dim3(HIDDIM / 64, MB), 256, 0, stream>>>(
        h, W_self1, hneigh, W_neigh1, b1, nullptr, h1, NNODES, HIDDIM, 256, 256);

    // ---- conv2 ----
    gemm_nt<false, false, true><<<dim3(512 / 64, MB), 256, 0, stream>>>(
        h1, W_ih2, nullptr, nullptr, b_ih2, b_hh2, Hin, NNODES, 512, 128, 0);
    lstm_mfma<128><<<dim3(NB), 256, 0, stream>>>(Hin, Wb2, nidx, hneigh, NNODES);
    gemm_nt<true, true, false><<<dim3(HIDDIM / 64, MB), 256, 0, stream>>>(
        h1, W_self2, hneigh, W_neigh2, b2, nullptr, h2, NNODES, HIDDIM, 128, 128);

    // ---- readout ----
    segmax_k<<<dim3(NGRAPH), 128, 0, stream>>>(h2, gids, hg, NNODES);
    cls_k<<<dim3((NGRAPH * NCLS + 255) / 256), 256, 0, stream>>>(hg, W_cls, b_cls, out);
}

// Round 3
// 3001.886 us; speedup vs baseline: 3.2326x; 2.1777x over previous
//
#include <hip/hip_runtime.h>
#include <hip/hip_bf16.h>

// SAGEClassifier: h[50000,256] --conv1(LSTM-agg)--> h1[50000,128] --conv2--> h2[50000,128]
//   --segment_max(256 graphs)--> hg[256,128] --linear--> out[256,10]
//
// Round 2: kill VGPR spills in lstm_mfma (round-1 demand ~260 VGPR > 256 cap ->
// 7 GB/dispatch scratch traffic, the whole 5.1 ms).
//  - TNODE=32 nodes/block (templated): c-state 32/thread, acc 32, m-tiles=2.
//  - hS double-buffered; h_new written directly to hS[next] (hn regs eliminated).
//  - last step writes hout directly from registers.
//  - gemm_nt still fp32 (isolate this change; MFMA-ize next round if dominant).

#define NNODES  50000
#define DEG     16
#define INDIM   256
#define HIDDIM  128
#define NCLS    10
#define NGRAPH  256

typedef __hip_bfloat16 bf16;
typedef short bf16x8 __attribute__((ext_vector_type(8)));
typedef float f32x4  __attribute__((ext_vector_type(4)));

__device__ __forceinline__ float sigf(float x) {
    x = fminf(fmaxf(x, -30.f), 30.f);
    return 1.0f / (1.0f + __expf(-x));
}
__device__ __forceinline__ float tanhfast(float x) {
    x = fminf(fmaxf(x, -15.f), 15.f);
    float e = __expf(2.0f * x);
    return (e - 1.0f) / (e + 1.0f);
}
__device__ __forceinline__ float b2f(unsigned short u) {
    return __uint_as_float(((unsigned)u) << 16);
}
__device__ __forceinline__ unsigned short f2b(float f) {  // RNE bf16
    unsigned u = __float_as_uint(f);
    return (unsigned short)((u + 0x7FFF + ((u >> 16) & 1)) >> 16);
}

__global__ void f2bf_k(const float* __restrict__ in, unsigned short* __restrict__ out, int n) {
    int i = blockIdx.x * 256 + threadIdx.x;
    if (i < n) out[i] = f2b(in[i]);
}

// ---------------- fp32 tiled GEMM (unchanged) ----------------
template<bool RELU, bool DUAL, bool BF16OUT>
__global__ __launch_bounds__(256) void gemm_nt(
    const float* __restrict__ A, const float* __restrict__ B,
    const float* __restrict__ A2, const float* __restrict__ B2,
    const float* __restrict__ bias0, const float* __restrict__ bias1,
    void* __restrict__ Cout, int M, int Ncol, int K, int K2)
{
    __shared__ float As[16][68];
    __shared__ float Bs[16][68];
    const int tid = threadIdx.x;
    const int m0 = blockIdx.y * 64;
    const int j0 = blockIdx.x * 64;
    const int tx = tid & 15;
    const int ty = tid >> 4;
    const int am = tid >> 2;
    const int ak = (tid & 3) * 4;
    float c[4][4] = {};

    const int npass = DUAL ? 2 : 1;
    for (int pass = 0; pass < npass; ++pass) {
        const float* Ap = (DUAL && pass) ? A2 : A;
        const float* Bp = (DUAL && pass) ? B2 : B;
        const int Kp = (DUAL && pass) ? K2 : K;
        for (int kk = 0; kk < Kp; kk += 16) {
            float4 av = make_float4(0.f, 0.f, 0.f, 0.f);
            float4 bv = make_float4(0.f, 0.f, 0.f, 0.f);
            if (m0 + am < M)    av = *(const float4*)&Ap[(size_t)(m0 + am) * Kp + kk + ak];
            if (j0 + am < Ncol) bv = *(const float4*)&Bp[(size_t)(j0 + am) * Kp + kk + ak];
            __syncthreads();
            As[ak + 0][am] = av.x; As[ak + 1][am] = av.y;
            As[ak + 2][am] = av.z; As[ak + 3][am] = av.w;
            Bs[ak + 0][am] = bv.x; Bs[ak + 1][am] = bv.y;
            Bs[ak + 2][am] = bv.z; Bs[ak + 3][am] = bv.w;
            __syncthreads();
            #pragma unroll
            for (int k = 0; k < 16; ++k) {
                float4 a = *(const float4*)&As[k][ty * 4];
                float4 b = *(const float4*)&Bs[k][tx * 4];
                c[0][0] = fmaf(a.x, b.x, c[0][0]); c[0][1] = fmaf(a.x, b.y, c[0][1]);
                c[0][2] = fmaf(a.x, b.z, c[0][2]); c[0][3] = fmaf(a.x, b.w, c[0][3]);
                c[1][0] = fmaf(a.y, b.x, c[1][0]); c[1][1] = fmaf(a.y, b.y, c[1][1]);
                c[1][2] = fmaf(a.y, b.z, c[1][2]); c[1][3] = fmaf(a.y, b.w, c[1][3]);
                c[2][0] = fmaf(a.z, b.x, c[2][0]); c[2][1] = fmaf(a.z, b.y, c[2][1]);
                c[2][2] = fmaf(a.z, b.z, c[2][2]); c[2][3] = fmaf(a.z, b.w, c[2][3]);
                c[3][0] = fmaf(a.w, b.x, c[3][0]); c[3][1] = fmaf(a.w, b.y, c[3][1]);
                c[3][2] = fmaf(a.w, b.z, c[3][2]); c[3][3] = fmaf(a.w, b.w, c[3][3]);
            }
        }
    }
    #pragma unroll
    for (int i = 0; i < 4; ++i) {
        int m = m0 + ty * 4 + i;
        if (m >= M) continue;
        #pragma unroll
        for (int jj = 0; jj < 4; ++jj) {
            int j = j0 + tx * 4 + jj;
            if (j >= Ncol) continue;
            float v = c[i][jj];
            if (bias0) v += bias0[j];
            if (bias1) v += bias1[j];
            if (RELU) v = fmaxf(v, 0.f);
            if (BF16OUT) ((bf16*)Cout)[(size_t)m * Ncol + j] = __float2bfloat16(v);
            else         ((float*)Cout)[(size_t)m * Ncol + j] = v;
        }
    }
}

// ---------------- MFMA fused LSTM ----------------
// Block: TNODE nodes, 256 threads (4 waves). Wave w owns d-cols [w*16,w*16+16) of each
// 64-d chunk, all 4 gates -> i/f/g/o of one (node,d) share a lane+reg (per-lane LSTM).
// C-fragment: node = m*16 + (lane>>4)*4 + reg, d = dc*64 + w*16 + (lane&15).
template<int D, int TNODE>
__global__ __launch_bounds__(256, 2) void lstm_mfma(
    const unsigned short* __restrict__ Hin,   // [Nn,4D] bf16 bits (bias folded)
    const unsigned short* __restrict__ Wb,    // [4D,D]  bf16 bits (W_hh row-major)
    const int* __restrict__ nidx,             // [Nn,DEG]
    float* __restrict__ hout,                 // [Nn,D]
    int Nn)
{
    constexpr int FD    = 4 * D;
    constexpr int KCH   = D / 32;      // K chunks of 32
    constexpr int DCH   = D / 64;      // d chunks of 64
    constexpr int MT    = TNODE / 16;  // MFMA m-tiles
    constexpr int LDA   = D + 8;       // hS row stride (16B-aligned rows)
    constexpr int LDH   = 264;         // hinS row stride (4 gates x 64 + 8 pad)
    constexpr int SITER = TNODE / 8;   // staging iterations

    __shared__ unsigned short hS[2][TNODE * LDA];   // double-buffered h_state
    __shared__ unsigned short hinS[TNODE * LDH];
    __shared__ int nidS[TNODE * DEG];

    const int tid  = threadIdx.x;
    const int wid  = tid >> 6;
    const int lane = tid & 63;
    const int lg   = lane >> 4;
    const int lr   = lane & 15;
    const int nb   = blockIdx.x * TNODE;

    for (int i = tid; i < TNODE * DEG; i += 256) {
        int node = nb + (i >> 4);
        nidS[i] = (node < Nn) ? nidx[node * DEG + (i & 15)] : 0;
    }

    float c[DCH][MT][4];
    #pragma unroll
    for (int dc = 0; dc < DCH; ++dc)
        #pragma unroll
        for (int m = 0; m < MT; ++m)
            #pragma unroll
            for (int r = 0; r < 4; ++r) c[dc][m][r] = 0.f;
    __syncthreads();

    int cur = 0;
    for (int t = 0; t < DEG; ++t) {
        #pragma unroll 1
        for (int dc = 0; dc < DCH; ++dc) {
            // ---- stage gathered Hin slice: TNODE rows x (4 gates x 64 cols) ----
            __syncthreads();   // hinS free; (dc==0) also orders prev step's hS writes
            uint4 stg[SITER];
            #pragma unroll
            for (int it = 0; it < SITER; ++it) {
                int i = tid + it * 256;
                int r = i >> 5, s = i & 31, g = s >> 3, c8 = s & 7;
                int nbr = nidS[r * DEG + t];
                stg[it] = *(const uint4*)&Hin[(size_t)nbr * FD + g * D + dc * 64 + c8 * 8];
            }
            #pragma unroll
            for (int it = 0; it < SITER; ++it) {
                int i = tid + it * 256;
                int r = i >> 5, s = i & 31;
                *(uint4*)&hinS[r * LDH + s * 8] = stg[it];
            }
            __syncthreads();

            // ---- acc init from gathered input transform ----
            f32x4 acc[4][MT];   // [gate][mtile]
            #pragma unroll
            for (int g = 0; g < 4; ++g)
                #pragma unroll
                for (int m = 0; m < MT; ++m)
                    #pragma unroll
                    for (int r = 0; r < 4; ++r)
                        acc[g][m][r] = b2f(hinS[(m * 16 + lg * 4 + r) * LDH + g * 64 + wid * 16 + lr]);

            // ---- recurrent GEMM: acc += h_state @ W_hh^T (wave's col slice) ----
            if (t > 0) {
                #pragma unroll
                for (int kk = 0; kk < KCH; ++kk) {
                    bf16x8 b[4];
                    #pragma unroll
                    for (int g = 0; g < 4; ++g)
                        b[g] = *(const bf16x8*)&Wb[(size_t)(g * D + dc * 64 + wid * 16 + lr) * D + kk * 32 + lg * 8];
                    #pragma unroll
                    for (int m = 0; m < MT; ++m) {
                        bf16x8 a = *(const bf16x8*)&hS[cur][(m * 16 + lr) * LDA + kk * 32 + lg * 8];
                        #pragma unroll
                        for (int g = 0; g < 4; ++g)
                            acc[g][m] = __builtin_amdgcn_mfma_f32_16x16x32_bf16(a, b[g], acc[g][m], 0, 0, 0);
                    }
                }
            }

            // ---- LSTM nonlinearity; h_new -> hS[next] (or hout on last step) ----
            #pragma unroll
            for (int m = 0; m < MT; ++m)
                #pragma unroll
                for (int r = 0; r < 4; ++r) {
                    float ig = sigf(acc[0][m][r]);
                    float fg = sigf(acc[1][m][r]);
                    float gg = tanhfast(acc[2][m][r]);
                    float og = sigf(acc[3][m][r]);
                    float cv = fg * c[dc][m][r] + ig * gg;
                    c[dc][m][r] = cv;
                    float hv = og * tanhfast(cv);
                    if (t < DEG - 1) {
                        hS[cur ^ 1][(m * 16 + lg * 4 + r) * LDA + dc * 64 + wid * 16 + lr] = f2b(hv);
                    } else {
                        int node = nb + m * 16 + lg * 4 + r;
                        if (node < Nn)
                            hout[(size_t)node * D + dc * 64 + wid * 16 + lr] = hv;
                    }
                }
        }
        cur ^= 1;
    }
}

// ---------------- readout ----------------
__global__ void segmax_k(const float* __restrict__ h2, const int* __restrict__ gid,
                         float* __restrict__ hg, int Nn) {
    int g = blockIdx.x;
    int d = threadIdx.x;   // 128
    __shared__ int sb[2];
    if (d < 2) {
        int target = g + d;
        int lo = 0, hi = Nn;
        while (lo < hi) { int mid = (lo + hi) >> 1; if (gid[mid] < target) lo = mid + 1; else hi = mid; }
        sb[d] = lo;
    }
    __syncthreads();
    int lo = sb[0], hi = sb[1];
    float m = -INFINITY;
    for (int r = lo; r < hi; ++r) m = fmaxf(m, h2[(size_t)r * HIDDIM + d]);
    hg[g * HIDDIM + d] = m;
}

__global__ void cls_k(const float* __restrict__ hg, const float* __restrict__ W,
                      const float* __restrict__ b, float* __restrict__ out) {
    int idx = blockIdx.x * 256 + threadIdx.x;
    if (idx >= NGRAPH * NCLS) return;
    int g = idx / NCLS, cc = idx % NCLS;
    float s = b[cc];
    const float* hp = hg + g * HIDDIM;
    const float* wp = W + cc * HIDDIM;
    #pragma unroll 8
    for (int k = 0; k < HIDDIM; ++k) s = fmaf(hp[k], wp[k], s);
    out[idx] = s;
}

extern "C" void kernel_launch(void* const* d_in, const int* in_sizes, int n_in,
                              void* d_out, int out_size, void* d_ws, size_t ws_size,
                              hipStream_t stream)
{
    const float* h       = (const float*)d_in[0];
    const int*   nidx    = (const int*)d_in[1];
    const int*   gids    = (const int*)d_in[2];
    const float* W_ih1   = (const float*)d_in[3];
    const float* W_hh1   = (const float*)d_in[4];
    const float* b_ih1   = (const float*)d_in[5];
    const float* b_hh1   = (const float*)d_in[6];
    const float* W_self1 = (const float*)d_in[7];
    const float* W_neigh1= (const float*)d_in[8];
    const float* b1      = (const float*)d_in[9];
    const float* W_ih2   = (const float*)d_in[10];
    const float* W_hh2   = (const float*)d_in[11];
    const float* b_ih2   = (const float*)d_in[12];
    const float* b_hh2   = (const float*)d_in[13];
    const float* W_self2 = (const float*)d_in[14];
    const float* W_neigh2= (const float*)d_in[15];
    const float* b2      = (const float*)d_in[16];
    const float* W_cls   = (const float*)d_in[17];
    const float* b_cls   = (const float*)d_in[18];
    float* out = (float*)d_out;

    // ws layout (16B-aligned chunks)
    char* ws = (char*)d_ws;
    unsigned short* Hin    = (unsigned short*)(ws);            // 102,400,000
    float*          hneigh = (float*)(ws + 102400000);         //  51,200,000
    float*          h1     = (float*)(ws + 153600000);         //  25,600,000
    float*          h2     = (float*)(ws + 179200000);         //  25,600,000
    float*          hg     = (float*)(ws + 204800000);         //     131,072
    unsigned short* Wb1    = (unsigned short*)(ws + 204931072);//     524,288
    unsigned short* Wb2    = (unsigned short*)(ws + 205455360);//     131,072

    // W_hh -> bf16 (row-major kept: B-fragment source)
    f2bf_k<<<dim3((262144 + 255) / 256), 256, 0, stream>>>(W_hh1, Wb1, 262144);
    f2bf_k<<<dim3((65536 + 255) / 256), 256, 0, stream>>>(W_hh2, Wb2, 65536);

    const int MB = (NNODES + 63) / 64;
    const int NB32 = (NNODES + 31) / 32;   // 1563 LSTM blocks

    // ---- conv1 ----
    gemm_nt<false, false, true><<<dim3(1024 / 64, MB), 256, 0, stream>>>(
        h, W_ih1, nullptr, nullptr, b_ih1, b_hh1, Hin, NNODES, 1024, 256, 0);
    lstm_mfma<256, 32><<<dim3(NB32), 256, 0, stream>>>(Hin, Wb1, nidx, hneigh, NNODES);
    gemm_nt<true, true, false><<<dim3(HIDDIM / 64, MB), 256, 0, stream>>>(
        h, W_self1, hneigh, W_neigh1, b1, nullptr, h1, NNODES, HIDDIM, 256, 256);

    // ---- conv2 ----
    gemm_nt<false, false, true><<<dim3(512 / 64, MB), 256, 0, stream>>>(
        h1, W_ih2, nullptr, nullptr, b_ih2, b_hh2, Hin, NNODES, 512, 128, 0);
    lstm_mfma<128, 32><<<dim3(NB32), 256, 0, stream>>>(Hin, Wb2, nidx, hneigh, NNODES);
    gemm_nt<true, true, false><<<dim3(HIDDIM / 64, MB), 256, 0, stream>>>(
        h1, W_self2, hneigh, W_neigh2, b2, nullptr, h2, NNODES, HIDDIM, 128, 128);

    // ---- readout ----
    segmax_k<<<dim3(NGRAPH), 128, 0, stream>>>(h2, gids, hg, NNODES);
    cls_k<<<dim3((NGRAPH * NCLS + 255) / 256), 256, 0, stream>>>(hg, W_cls, b_cls, out);
}